// Round 26
// baseline (81.713 us; speedup 1.0000x reference)
//
#include <hip/hip_runtime.h>
#include <hip/hip_bf16.h>

// StyledConv: B=8, Cin=Cout=64, H=W=256, S=512, K=3
#define BB   8
#define CC   64
#define HH   256
#define WW   256
#define SS   512
#define HW   (HH*WW)

#define LIN_SCALE  0.044194173824159216f   // 1/sqrt(512)
#define CONV_SCALE 0.041666666666666664f   // 1/24
#define LRELU      0.2f
#define GAIN       1.4142135623730951f

// conv tile: 8 rows x 32 cols out, all 64 co, all 64 ci staged once
#define TY 8
#define TX 32
#define LY (TY + 2)   // 10
#define LX (TX + 2)   // 34
#define WLE (9 * 8 * 64 * 8)        // weight elems per image

typedef __attribute__((ext_vector_type(8)))  short short8;     // A/B frag (8 bf16)
typedef __attribute__((ext_vector_type(16))) float floatx16;   // 32x32 C/D frag

static __device__ __forceinline__ unsigned short f2bf(float f) {
    unsigned u = __float_as_uint(f);
    u += 0x7FFF + ((u >> 16) & 1);          // RNE (inputs finite)
    return (unsigned short)(u >> 16);
}

// packed f32x2 -> bf16x2 (v_cvt_pk_bf16_f32): low = a, high = b
static __device__ __forceinline__ unsigned pk2(float a, float b) {
    __hip_bfloat162 h = __float22bfloat162_rn(make_float2(a, b));
    return *(unsigned*)&h;
}

#define VC(vv,kk) ((kk)==0?(vv).x:((kk)==1?(vv).y:((kk)==2?(vv).z:(vv).w)))

// ---------------- Kernel P: fused prep (mod + wmod), ONE launch (R25)
__global__ void prep_kernel(const float* __restrict__ style,
                            const float* __restrict__ mod_w,
                            const float* __restrict__ mod_b,
                            const float* __restrict__ weight,
                            unsigned short* __restrict__ wbf) {
    __shared__ float part[256];
    __shared__ float s_l[64];
    const int blk = blockIdx.x;       // b*8 + cog
    const int b = blk >> 3, cog = blk & 7;
    const int t = threadIdx.x;

    // ---- phase 1: s (parallel dot: 4-way k-split over 256 threads)
    {
        int ci = t & 63, kp = t >> 6;
        const float* st = style + b * SS + kp * 128;
        float acc = 0.f;
        for (int k = 0; k < 128; ++k)
            acc = fmaf(st[k], mod_w[(kp * 128 + k) * CC + ci], acc);
        part[t] = acc;
    }
    __syncthreads();
    if (t < 64) {
        float v = part[t] + part[t + 64] + part[t + 128] + part[t + 192];
        s_l[t] = (v * LIN_SCALE + mod_b[t]) * CONV_SCALE;
    }
    __syncthreads();

    // ---- phase 2: wmod for co = cog*8 + wv*2 + {0,1}; lane = ci
    const int wv = t >> 6;
    const int ci = t & 63;
    const float sv = s_l[ci];
    const int g = ci >> 3, j = ci & 7;
#pragma unroll
    for (int cc = 0; cc < 2; ++cc) {
        int co = cog * 8 + wv * 2 + cc;
        float wvv[9];
        float sum = 0.f;
        const float* wp = weight + (co * CC + ci) * 9;
#pragma unroll
        for (int k = 0; k < 9; ++k) {
            wvv[k] = wp[k] * sv;
            sum = fmaf(wvv[k], wvv[k], sum);
        }
#pragma unroll
        for (int off = 32; off; off >>= 1)
            sum += __shfl_xor(sum, off);
        float demod = rsqrtf(sum + 1e-8f);
#pragma unroll
        for (int ko = 0; ko < 9; ++ko) {
            size_t idx = ((((size_t)b * 9 + ko) * 8 + g) * 64 + co) * 8 + j;
            wbf[idx] = f2bf(wvv[ko] * demod);
        }
    }
}

// ---------------- Kernel C: implicit-GEMM conv, MFMA 32x32x16 bf16
// 256 thr (4 waves). Wave wv owns rows wv*2..wv*2+1 and ALL 64 co.
// A-frags from GLOBAL wbf via DEPTH-4 prefetch ring (lead ~96-128 cyc,
// covers most of L2 latency; ring slot s&3 = compile-time -> registers).
// B-frags from xs LDS [g8][y10][x34][8ci] (contiguous conflict-free reads).
__global__ __launch_bounds__(256, 3) void conv_kernel(
        const float* __restrict__ x,
        const float* __restrict__ noise,
        const float* __restrict__ nwp,
        const float* __restrict__ bias,
        const unsigned short* __restrict__ wbf,
        float* __restrict__ out) {
    __shared__ unsigned short xs[8 * LY * LX * 8];   // 43520 B

    // bijective XCD swizzle: XCD c -> batch image b=c (256 blocks per image)
    const int lin  = blockIdx.x;                 // 0..2047
    const int lin2 = (lin & 7) * 256 + (lin >> 3);
    const int b   = lin2 >> 8;
    const int rem = lin2 & 255;
    const int by  = rem >> 3;      // 0..31
    const int bx  = rem & 7;       // 0..7
    const int x0t = bx * TX;
    const int y0t = by * TY;

    const int t = threadIdx.x;
    const int lane = t & 63;
    const int wv = t >> 6;         // wave 0..3 -> row pair
    const int n31 = lane & 31;
    const int h   = lane >> 5;     // k-slice half

    // ---- early prefetch: A-ring (4 steps) + noise, independent of staging
    const unsigned short* wb = wbf + (size_t)b * WLE;
#define ALOAD(ko, kc, m) \
    (*(const short8*)&wb[((((ko) * 8 + (kc) * 2 + h) * 64) + (m) * 32 + n31) * 8])
    short8 r0[4], r1[4];
#pragma unroll
    for (int s = 0; s < 4; ++s) {
        r0[s] = ALOAD(s >> 2, s & 3, 0);
        r1[s] = ALOAD(s >> 2, s & 3, 1);
    }
    const float nw = nwp[0];
    float nzr0 = noise[(size_t)b * HW + (size_t)(y0t + wv * 2)     * WW + x0t + n31];
    float nzr1 = noise[(size_t)b * HW + (size_t)(y0t + wv * 2 + 1) * WW + x0t + n31];
    __builtin_amdgcn_sched_barrier(0);   // pin prefetches above staging

    // ---- stage x: 800 tasks; 2 batches x 2 tasks per thread
#pragma unroll
    for (int bt = 0; bt < 2; ++bt) {
        int na = t + bt * 512;  na = na < 799 ? na : 799;
        int nb = na + 256;      nb = nb < 799 ? nb : 799;

        int qa = na % 10, ra = na / 10, yla = ra % 10, ga = ra / 10;
        int qb = nb % 10, rb = nb / 10, ylb = rb % 10, gb = rb / 10;
        int gya = y0t + yla - 1, gyb = y0t + ylb - 1;
        int gx0a = x0t - 4 + qa * 4, gx0b = x0t - 4 + qb * 4;
        bool rowoka = (unsigned)gya < (unsigned)HH;
        bool rowokb = (unsigned)gyb < (unsigned)HH;
        int gyca  = gya < 0 ? 0 : (gya > HH - 1 ? HH - 1 : gya);
        int gycb  = gyb < 0 ? 0 : (gyb > HH - 1 ? HH - 1 : gyb);
        int gx0ca = gx0a < 0 ? 0 : (gx0a > WW - 4 ? WW - 4 : gx0a);
        int gx0cb = gx0b < 0 ? 0 : (gx0b > WW - 4 ? WW - 4 : gx0b);
        const float* xpa = x + ((size_t)b * CC + ga * 8) * HW + (size_t)gyca * WW + gx0ca;
        const float* xpb = x + ((size_t)b * CC + gb * 8) * HW + (size_t)gycb * WW + gx0cb;

        float4 va[8], vb2[8];
#pragma unroll
        for (int j = 0; j < 8; ++j) va[j]  = *(const float4*)(xpa + (size_t)j * HW);
#pragma unroll
        for (int j = 0; j < 8; ++j) vb2[j] = *(const float4*)(xpb + (size_t)j * HW);
        __builtin_amdgcn_sched_barrier(0);   // both load batches issued first

#pragma unroll
        for (int k = 0; k < 4; ++k) {
            int lx = 4 * qa - 3 + k;
            if ((unsigned)lx < (unsigned)LX) {
                bool ok = rowoka && ((unsigned)(gx0a + k) < (unsigned)WW);
                uint4 w;
                w.x = ok ? pk2(VC(va[0], k), VC(va[1], k)) : 0u;
                w.y = ok ? pk2(VC(va[2], k), VC(va[3], k)) : 0u;
                w.z = ok ? pk2(VC(va[4], k), VC(va[5], k)) : 0u;
                w.w = ok ? pk2(VC(va[6], k), VC(va[7], k)) : 0u;
                *(uint4*)&xs[((ga * LY + yla) * LX + lx) * 8] = w;
            }
        }
#pragma unroll
        for (int k = 0; k < 4; ++k) {
            int lx = 4 * qb - 3 + k;
            if ((unsigned)lx < (unsigned)LX) {
                bool ok = rowokb && ((unsigned)(gx0b + k) < (unsigned)WW);
                uint4 w;
                w.x = ok ? pk2(VC(vb2[0], k), VC(vb2[1], k)) : 0u;
                w.y = ok ? pk2(VC(vb2[2], k), VC(vb2[3], k)) : 0u;
                w.z = ok ? pk2(VC(vb2[4], k), VC(vb2[5], k)) : 0u;
                w.w = ok ? pk2(VC(vb2[6], k), VC(vb2[7], k)) : 0u;
                *(uint4*)&xs[((gb * LY + ylb) * LX + lx) * 8] = w;
            }
        }
    }
    __syncthreads();

    // ---- compute: flat 36 steps; ring-4 A-prefetch; B from LDS
    floatx16 acc[2][2];
    acc[0][0] = (floatx16)0.f; acc[0][1] = (floatx16)0.f;
    acc[1][0] = (floatx16)0.f; acc[1][1] = (floatx16)0.f;

#pragma unroll
    for (int s = 0; s < 36; ++s) {
        const int ko = s >> 2, kc = s & 3;
        const int kh = ko / 3, kw = ko % 3;
        const int sl = s & 3;
        short8 c0 = r0[sl], c1 = r1[sl];
        // issue replacement load for step s+4 (lead ~4 steps ≈ 128 cyc)
        if (s + 4 < 36) {
            const int ns = s + 4;
            r0[sl] = ALOAD(ns >> 2, ns & 3, 0);
            r1[sl] = ALOAD(ns >> 2, ns & 3, 1);
        }
        const int g = kc * 2 + h;
#pragma unroll
        for (int rl = 0; rl < 2; ++rl) {
            int ys = wv * 2 + rl + kh;
            short8 bv = *(const short8*)&xs[((g * LY + ys) * LX + kw + n31) * 8];
            __builtin_amdgcn_s_setprio(1);
            acc[rl][0] = __builtin_amdgcn_mfma_f32_32x32x16_bf16(
                c0, bv, acc[rl][0], 0, 0, 0);
            acc[rl][1] = __builtin_amdgcn_mfma_f32_32x32x16_bf16(
                c1, bv, acc[rl][1], 0, 0, 0);
            __builtin_amdgcn_s_setprio(0);
        }
    }
#undef ALOAD

    // ---- epilogue: noise + bias + leaky_relu * gain
    // D layout (32x32): col px = lane&31, row co32 = (reg&3) + 8*(reg>>2) + 4*h
#pragma unroll
    for (int rl = 0; rl < 2; ++rl) {
        int py = y0t + wv * 2 + rl;
        float nz = nw * (rl ? nzr1 : nzr0);
#pragma unroll
        for (int reg = 0; reg < 16; ++reg) {
            int cr = (reg & 3) + 8 * (reg >> 2) + 4 * h;
            float v0 = acc[rl][0][reg] + nz + bias[cr];
            v0 = (v0 > 0.f ? v0 : LRELU * v0) * GAIN;
            out[((size_t)b * CC + cr) * HW + (size_t)py * WW + x0t + n31] = v0;
            float v1 = acc[rl][1][reg] + nz + bias[32 + cr];
            v1 = (v1 > 0.f ? v1 : LRELU * v1) * GAIN;
            out[((size_t)b * CC + 32 + cr) * HW + (size_t)py * WW + x0t + n31] = v1;
        }
    }
}

extern "C" void kernel_launch(void* const* d_in, const int* in_sizes, int n_in,
                              void* d_out, int out_size, void* d_ws, size_t ws_size,
                              hipStream_t stream) {
    const float* x       = (const float*)d_in[0];
    const float* style   = (const float*)d_in[1];
    const float* noise   = (const float*)d_in[2];
    const float* weight  = (const float*)d_in[3];
    const float* mod_w   = (const float*)d_in[4];
    const float* mod_b   = (const float*)d_in[5];
    const float* nw      = (const float*)d_in[6];
    const float* bias    = (const float*)d_in[7];
    float* out = (float*)d_out;

    unsigned short* wbf   = (unsigned short*)((char*)d_ws + 4096); // 576 KB

    prep_kernel<<<dim3(BB * 8), dim3(256), 0, stream>>>(
        style, mod_w, mod_b, weight, wbf);
    conv_kernel<<<dim3((WW / TX) * (HH / TY) * BB), dim3(256), 0, stream>>>(
        x, noise, nw, bias, wbf, out);
}